// Round 13
// baseline (3024.922 us; speedup 1.0000x reference)
//
#include <hip/hip_runtime.h>
#include <hip/hip_bf16.h>

// ============================================================================
// SimpleGatedUnit. R13 = R12 (4 batch domains x 32 col-blocks, 1 wave each,
// frag-major exchange, LDS-transpose publish) with VIRGIN-SLOT exchange:
// every round publishes into a fresh 64KB slot (4 domains x 16KB). Producers:
// sc0sc1 data stores -> vmcnt(0) -> sc flag (monotonic phase). Consumers:
// poll ONE 128B flag line (cheap retries) -> PLAIN CACHED bulk read of the
// slot (first touch on this XCD => L2 miss => post-flag IC fill; co-XCD
// blocks L2-hit). Read amplification 32x -> 8x, no fences, no resets.
// Slot reuse only across kernel dispatches (inter-kernel acquire invalidates
// caches). Slot order permuted (*97 mod nslots) against stream prefetch.
// ============================================================================

typedef __attribute__((ext_vector_type(4))) float  f32x4;
typedef __attribute__((ext_vector_type(4))) float  floatx4;
typedef __attribute__((ext_vector_type(8))) short  short8;
typedef __attribute__((ext_vector_type(4))) short  short4v;
typedef __attribute__((ext_vector_type(2))) int    int2v;

#define NSTEP  511
#define NGRP   4           // independent batch domains (16 rows each)
#define NCOLB  32          // column blocks per domain (16 cols each)

// ws layout (bytes)
#define OFF_FLG  0                        // int flags[4][32] (512 B)
#define OFF_HIN  4096                     // h-init frag-major (64 KB)
#define OFF_HF32 (OFF_HIN + 65536)        // h fp32 [64][512] row-major (128 KB)
#define OFF_UPK  (OFF_HF32 + 131072)      // packed U,U_in,U_out bf16  (1.5 MB)
#define OFF_WT   (OFF_UPK + 1572864)      // W^T bf16 [3][512 n][512 k](1.5 MB)
#define OFF_XCH  (OFF_WT + 1572864)       // exchange slot ring + xx segment
#define PER_T_BYTES 196608u               // xx bytes per time row
#define SLOT_BYTES  65536u                // one exchange slot (4 x 16 KB)

__device__ __forceinline__ float b2f(short s) {
  unsigned u = ((unsigned)(unsigned short)s) << 16;
  return __builtin_bit_cast(float, u);
}
__device__ __forceinline__ short f2b(float f) {  // RNE fp32->bf16
  unsigned u = __builtin_bit_cast(unsigned, f);
  u += 0x7fffu + ((u >> 16) & 1u);
  return (short)(u >> 16);
}
__device__ __forceinline__ float hsig(float x) {
  return fminf(fmaxf(0.2f * x + 0.5f, 0.0f), 1.0f);
}
__device__ __forceinline__ float softplus_f(float x) {
  return fmaxf(x, 0.0f) + log1pf(expf(-fabsf(x)));
}

// 8B store to the agent coherence point (IC)
__device__ __forceinline__ void st8_cp(short* p, int2v v) {
  asm volatile("global_store_dwordx2 %0, %1, off sc0 sc1"
               :: "v"(p), "v"(v) : "memory");
}

// 16 x 16B PLAIN CACHED fragment loads in ONE asm block (virgin address:
// first touch per XCD misses to IC post-flag; then L2-served).
__device__ __forceinline__ void ld_frags16(const short* p0, const short* p1,
                                           const short* p2, const short* p3,
                                           short8 f[16]) {
  short8 f0,f1,f2,f3,f4,f5,f6,f7,f8,f9,f10,f11,f12,f13,f14,f15;
  asm volatile(
    "global_load_dwordx4 %0,  %16, off\n\t"
    "global_load_dwordx4 %1,  %16, off offset:1024\n\t"
    "global_load_dwordx4 %2,  %16, off offset:2048\n\t"
    "global_load_dwordx4 %3,  %16, off offset:3072\n\t"
    "global_load_dwordx4 %4,  %17, off\n\t"
    "global_load_dwordx4 %5,  %17, off offset:1024\n\t"
    "global_load_dwordx4 %6,  %17, off offset:2048\n\t"
    "global_load_dwordx4 %7,  %17, off offset:3072\n\t"
    "global_load_dwordx4 %8,  %18, off\n\t"
    "global_load_dwordx4 %9,  %18, off offset:1024\n\t"
    "global_load_dwordx4 %10, %18, off offset:2048\n\t"
    "global_load_dwordx4 %11, %18, off offset:3072\n\t"
    "global_load_dwordx4 %12, %19, off\n\t"
    "global_load_dwordx4 %13, %19, off offset:1024\n\t"
    "global_load_dwordx4 %14, %19, off offset:2048\n\t"
    "global_load_dwordx4 %15, %19, off offset:3072\n\t"
    "s_waitcnt vmcnt(0)"
    : "=&v"(f0), "=&v"(f1), "=&v"(f2), "=&v"(f3),
      "=&v"(f4), "=&v"(f5), "=&v"(f6), "=&v"(f7),
      "=&v"(f8), "=&v"(f9), "=&v"(f10), "=&v"(f11),
      "=&v"(f12), "=&v"(f13), "=&v"(f14), "=&v"(f15)
    : "v"(p0), "v"(p1), "v"(p2), "v"(p3)
    : "memory");
  f[0]=f0; f[1]=f1; f[2]=f2; f[3]=f3; f[4]=f4; f[5]=f5; f[6]=f6; f[7]=f7;
  f[8]=f8; f[9]=f9; f[10]=f10; f[11]=f11; f[12]=f12; f[13]=f13; f[14]=f14; f[15]=f15;
}

// poll this domain's 32 flags (one 128B line) until all >= phase
__device__ __forceinline__ void poll_flags(const int* fl, int lane, int phase) {
  const int* fp = fl + (lane & 31);
  int guard = 0;
  for (;;) {
    int f = __hip_atomic_load(fp, __ATOMIC_RELAXED, __HIP_MEMORY_SCOPE_AGENT);
    if (__all(f >= phase)) break;
    if (++guard > (1 << 15)) break;  // safety valve: degrade, never hang
  }
}

// ---------------------------------------------------------------------------
// prep: pack U mats into B-fragment order bf16; transpose W mats to [n][k]
// Upk[mat][c][kb][lane][j] = U[kb*32 + (lane>>4)*8 + j][c*16 + (lane&15)]
// ---------------------------------------------------------------------------
__global__ __launch_bounds__(256) void prep_kernel(
    const float* __restrict__ U0, const float* __restrict__ U1, const float* __restrict__ U2,
    const float* __restrict__ W0, const float* __restrict__ W1, const float* __restrict__ W2,
    short* __restrict__ Upk, short* __restrict__ Wt)
{
  int e = blockIdx.x * 256 + threadIdx.x;
  if (e < 786432) {
    int mat = e >> 18;
    int rem = e & 262143;
    int c   = rem >> 13;
    int r2  = rem & 8191;
    int kb  = r2 >> 9;
    int r3  = r2 & 511;
    int l = r3 >> 3, j = r3 & 7;
    int k = kb * 32 + ((l >> 4) << 3) + j;
    int d = c * 16 + (l & 15);
    const float* U = (mat == 0) ? U0 : (mat == 1 ? U1 : U2);
    Upk[e] = f2b(U[k * 512 + d]);
  } else if (e < 1572864) {
    int e2 = e - 786432;
    int mat = e2 >> 18;
    int rem = e2 & 262143;
    int n = rem >> 9, k = rem & 511;
    const float* W = (mat == 0) ? W0 : (mat == 1 ? W1 : W2);
    Wt[e2] = f2b(W[k * 512 + n]);
  }
}

__global__ __launch_bounds__(256) void init0_kernel(float* h_f32) {
  int e = blockIdx.x * 256 + threadIdx.x;
  if (e < 32768) h_f32[e] = 0.0f;
}

// per-segment: zero flags; convert h_f32 -> hinit (frag-major per domain)
__global__ __launch_bounds__(256) void init_seg_kernel(
    const float* __restrict__ h_f32, short* __restrict__ hinit, int* flags)
{
  int e = blockIdx.x * 256 + threadIdx.x;
  if (e < 128) flags[e] = 0;
  if (e < 32768) {
    int d = e >> 13, i = e & 8191;
    int k = ((i >> 9) << 5) | (((i >> 7) & 3) << 3) | (i & 7);
    int row = d * 16 + ((i >> 3) & 15);
    hinit[e] = f2b(h_f32[row * 512 + k]);
  }
}

// ---------------------------------------------------------------------------
// GEMM (per segment): out[mat][m][n] = bf16( X-row(base+m) . W[mat][:,n] + b )
// ---------------------------------------------------------------------------
__global__ __launch_bounds__(256) void gemm_xw(
    const float* __restrict__ X, const short* __restrict__ Wt,
    const float* __restrict__ bias0, const float* __restrict__ bias1,
    const float* __restrict__ bias2, short* __restrict__ out,
    int base_row, int cnt_rows)
{
  __shared__ __align__(16) short Al[128][48];
  __shared__ __align__(16) short Bl[128][48];
  const int bm = blockIdx.x, bn = blockIdx.y, mat = blockIdx.z;
  const short* Wm = Wt + (size_t)mat * (512 * 512);
  const float* bias = (mat == 0) ? bias0 : (mat == 1 ? bias1 : bias2);
  short* om = out + (size_t)mat * ((size_t)cnt_rows * 512);
  const int tid = threadIdx.x, lane = tid & 63, wid = tid >> 6;
  const int wm = wid >> 1, wn = wid & 1;
  const int m0 = bm * 128, n0g = bn * 128;
  f32x4 acc[4][4];
  #pragma unroll
  for (int i = 0; i < 4; ++i)
    #pragma unroll
    for (int j = 0; j < 4; ++j) acc[i][j] = (f32x4){0.f, 0.f, 0.f, 0.f};

  for (int k0 = 0; k0 < 512; k0 += 32) {
    #pragma unroll
    for (int i = 0; i < 4; ++i) {
      int q = tid + 256 * i;
      int r = q >> 3, seg = q & 7;
      int ml = m0 + r;
      short4v h4 = {0, 0, 0, 0};
      if (ml < cnt_rows) {
        int gl = base_row + ml;
        int t = gl >> 6, bb = gl & 63;
        floatx4 v = *(const floatx4*)(X + ((size_t)bb * 512 + t) * 512 + k0 + seg * 4);
        h4 = (short4v){ f2b(v[0]), f2b(v[1]), f2b(v[2]), f2b(v[3]) };
      }
      *(short4v*)&Al[r][seg * 4] = h4;
    }
    #pragma unroll
    for (int i = 0; i < 2; ++i) {
      int q = tid + 256 * i;
      int r = q >> 2, seg = q & 3;
      *(short8*)&Bl[r][seg * 8] = *(const short8*)(Wm + (size_t)(n0g + r) * 512 + k0 + seg * 8);
    }
    __syncthreads();
    const int ko = (lane >> 4) * 8;
    short8 af[4], bf4[4];
    #pragma unroll
    for (int mt = 0; mt < 4; ++mt)
      af[mt] = *(const short8*)&Al[wm * 64 + mt * 16 + (lane & 15)][ko];
    #pragma unroll
    for (int nt = 0; nt < 4; ++nt)
      bf4[nt] = *(const short8*)&Bl[wn * 64 + nt * 16 + (lane & 15)][ko];
    #pragma unroll
    for (int mt = 0; mt < 4; ++mt)
      #pragma unroll
      for (int nt = 0; nt < 4; ++nt)
        acc[mt][nt] = __builtin_amdgcn_mfma_f32_16x16x32_bf16(af[mt], bf4[nt], acc[mt][nt], 0, 0, 0);
    __syncthreads();
  }
  const int rq = lane >> 4, cq = lane & 15;
  #pragma unroll
  for (int mt = 0; mt < 4; ++mt) {
    #pragma unroll
    for (int nt = 0; nt < 4; ++nt) {
      int n = n0g + wn * 64 + nt * 16 + cq;
      float bv = bias[n];
      #pragma unroll
      for (int rr = 0; rr < 4; ++rr) {
        int m = m0 + wm * 64 + mt * 16 + rq * 4 + rr;
        if (m < cnt_rows) om[(size_t)m * 512 + n] = f2b(acc[mt][nt][rr] + bv);
      }
    }
  }
}

// ---------------------------------------------------------------------------
// scan segment: 128 blocks x 64 threads. Domain d = blk>>5 (rows d*16..+16);
// block c = blk&31 (cols c*16..+16). U slices in LDS.
// Slots: g(s) -> slot 2s (phase 2s+1), h(s) -> slot 2s+1 (phase 2s+2).
// Slot address permuted: pm = (slot*97) % nslots.
// Per-domain sub-buffer: d*8192 shorts; frag-major as R12.
// ---------------------------------------------------------------------------
__global__ __launch_bounds__(64, 1) void scan_kernel(
    const short* __restrict__ hinit, short* xch, float* h_f32,
    const short* __restrict__ Upk,
    const short* __restrict__ xx,
    int* flags,
    const float* __restrict__ bu_in, const float* __restrict__ bu_out,
    float* __restrict__ out,
    int s0, int nsteps, int nt, int nslots)
{
  __shared__ __align__(16) short Ub[3][16][64][8];   // 48 KB, B-frag-packed
  __shared__ __align__(16) short St[256];            // wave transpose stage
  const int lane = threadIdx.x & 63;
  const int d = blockIdx.x >> 5;          // batch domain
  const int c = blockIdx.x & 31;          // column owner
  {
    const size_t cs = (size_t)c * 8192;
    short8* dst = (short8*)Ub;
    for (int i = lane; i < 3072; i += 64) {
      int mat = i >> 10;
      int rem = i & 1023;
      dst[i] = *(const short8*)(Upk + (size_t)mat * 262144 + cs + (size_t)rem * 8);
    }
  }
  const int colg = c * 16 + (lane & 15);
  const float binr  = bu_in[colg];
  const float boutr = bu_out[colg];
  const size_t XSZ = (size_t)nt * 64 * 512;
  const int dbase = d * 8192;             // domain sub-buffer (shorts)
  // consume base offset within domain buffer
  const int fofs = dbase + ((lane >> 4) << 7) + ((lane & 15) << 3);
  // publish offset: block slice (512B) + lane*4 shorts
  const int pofs = dbase + (c << 8) + (lane << 2);
  // St transpose write index
  const int sw = ((lane & 15) >> 3) * 128 + ((lane >> 4) << 5) + (lane & 7);
  int* fl = flags + d * 32;

  float hown[4];
  #pragma unroll
  for (int r = 0; r < 4; ++r)
    hown[r] = h_f32[(size_t)(d * 16 + (lane >> 4) * 4 + r) * 512 + colg];
  __syncthreads();

  for (int s = 0; s < nsteps; ++s) {
    // hoisted xx loads (cached) — overlap with poll
    float a1[4], a0[4], p1[4], p0[4];
    #pragma unroll
    for (int r = 0; r < 4; ++r) {
      int gr = d * 16 + (lane >> 4) * 4 + r;
      size_t i1 = ((size_t)(s + 1) * 64 + gr) * 512 + colg;
      size_t i0 = ((size_t)s * 64 + gr) * 512 + colg;
      a1[r] = b2f(xx[i1]);       a0[r] = b2f(xx[i0]);
      p1[r] = b2f(xx[XSZ + i1]); p0[r] = b2f(xx[XSZ + i0]);
    }

    // ---- stage 1: obtain h(s-1), then h@U, h@U_in ----
    short8 afr[16];
    if (s == 0) {
      const short* hb = hinit + fofs;      // kernel-ordered, no poll
      ld_frags16(hb, hb + 2048, hb + 4096, hb + 6144, afr);
    } else {
      poll_flags(fl, lane, 2 * s);         // h(s-1) published
      const short* hb = xch + (size_t)(((2 * s - 1) * 97) % nslots) * 32768 + fofs;
      ld_frags16(hb, hb + 2048, hb + 4096, hb + 6144, afr);
    }
    f32x4 accu  = {0.f, 0.f, 0.f, 0.f};
    f32x4 accin = {0.f, 0.f, 0.f, 0.f};
    #pragma unroll
    for (int kb = 0; kb < 16; ++kb) {
      short8 b0 = *((const short8*)Ub + ((0 * 16 + kb) * 64 + lane));
      short8 b1 = *((const short8*)Ub + ((1 * 16 + kb) * 64 + lane));
      accu  = __builtin_amdgcn_mfma_f32_16x16x32_bf16(afr[kb], b0, accu, 0, 0, 0);
      accin = __builtin_amdgcn_mfma_f32_16x16x32_bf16(afr[kb], b1, accin, 0, 0, 0);
    }
    float zr[4];
    #pragma unroll
    for (int r = 0; r < 4; ++r) {
      zr[r] = hsig(a1[r] + accu[r] + a0[r]);
      float zin = hsig(p1[r] + accin[r] + p0[r] + binr);
      St[sw + r * 8] = f2b(zin * hown[r]);
    }
    // publish g(s) into virgin slot 2s; drain; lane 0 sets flag = 2s+1
    {
      short* gslot = xch + (size_t)(((2 * s) * 97) % nslots) * 32768 + pofs;
      st8_cp(gslot, *(const int2v*)&St[lane << 2]);
      asm volatile("s_waitcnt vmcnt(0)" ::: "memory");
      if (lane == 0)
        __hip_atomic_store(&fl[c], 2 * s + 1, __ATOMIC_RELAXED, __HIP_MEMORY_SCOPE_AGENT);
    }

    // hoisted xx loads for stage 2
    float q1[4], q0[4];
    #pragma unroll
    for (int r = 0; r < 4; ++r) {
      int gr = d * 16 + (lane >> 4) * 4 + r;
      size_t i1 = ((size_t)(s + 1) * 64 + gr) * 512 + colg;
      size_t i0 = ((size_t)s * 64 + gr) * 512 + colg;
      q1[r] = b2f(xx[2 * XSZ + i1]); q0[r] = b2f(xx[2 * XSZ + i0]);
    }

    // ---- stage 2: poll g(s), then (z_in*h)@U_out ----
    poll_flags(fl, lane, 2 * s + 1);
    short8 gfr[16];
    {
      const short* gb = xch + (size_t)(((2 * s) * 97) % nslots) * 32768 + fofs;
      ld_frags16(gb, gb + 2048, gb + 4096, gb + 6144, gfr);
    }
    f32x4 acco = {0.f, 0.f, 0.f, 0.f};
    #pragma unroll
    for (int kb = 0; kb < 16; ++kb) {
      short8 b2 = *((const short8*)Ub + ((2 * 16 + kb) * 64 + lane));
      acco = __builtin_amdgcn_mfma_f32_16x16x32_bf16(gfr[kb], b2, acco, 0, 0, 0);
    }
    #pragma unroll
    for (int r = 0; r < 4; ++r) {
      int gr = d * 16 + (lane >> 4) * 4 + r;
      float pre = q1[r] + acco[r] + q0[r] + boutr;
      float zo = softplus_f(pre);
      float hn = (1.0f - zr[r]) * hown[r] + zr[r] * zo;
      hown[r] = hn;
      St[sw + r * 8] = f2b(hn);
      if (s0 + s == NSTEP - 1) out[(size_t)gr * 512 + colg] = hn;
    }
    // publish h(s) into virgin slot 2s+1 (skip at last local step)
    if (s < nsteps - 1) {
      short* hslot = xch + (size_t)(((2 * s + 1) * 97) % nslots) * 32768 + pofs;
      st8_cp(hslot, *(const int2v*)&St[lane << 2]);
      asm volatile("s_waitcnt vmcnt(0)" ::: "memory");
      if (lane == 0)
        __hip_atomic_store(&fl[c], 2 * s + 2, __ATOMIC_RELAXED, __HIP_MEMORY_SCOPE_AGENT);
    }
  }
  // persist fp32 h for the next segment
  #pragma unroll
  for (int r = 0; r < 4; ++r)
    h_f32[(size_t)(d * 16 + (lane >> 4) * 4 + r) * 512 + colg] = hown[r];
  asm volatile("s_waitcnt vmcnt(0)" ::: "memory");
}

extern "C" void kernel_launch(void* const* d_in, const int* in_sizes, int n_in,
                              void* d_out, int out_size, void* d_ws, size_t ws_size,
                              hipStream_t stream)
{
  const float* X      = (const float*)d_in[0];
  const float* W      = (const float*)d_in[1];
  const float* b      = (const float*)d_in[2];
  const float* W_in   = (const float*)d_in[3];
  const float* b_in   = (const float*)d_in[4];
  const float* W_out  = (const float*)d_in[5];
  const float* b_out  = (const float*)d_in[6];
  const float* U      = (const float*)d_in[7];
  const float* U_in   = (const float*)d_in[8];
  const float* U_out  = (const float*)d_in[9];
  const float* bu_in  = (const float*)d_in[10];
  const float* bu_out = (const float*)d_in[11];
  float* out = (float*)d_out;
  char* ws = (char*)d_ws;
  int*   flags = (int*)(ws + OFF_FLG);
  short* hinit = (short*)(ws + OFF_HIN);
  float* h_f32 = (float*)(ws + OFF_HF32);
  short* Upk   = (short*)(ws + OFF_UPK);
  short* Wt    = (short*)(ws + OFF_WT);

  // segment sizing: SEG*(2 slots + xx row) + 1 extra xx row
  size_t avail = (ws_size > (size_t)OFF_XCH) ? ws_size - (size_t)OFF_XCH : 0;
  long long per_step = 2LL * SLOT_BYTES + PER_T_BYTES;   // 327680
  int SEG = (int)((avail > PER_T_BYTES) ? (avail - PER_T_BYTES) / per_step : 0);
  if (SEG > NSTEP) SEG = NSTEP;
  if (SEG < 1) SEG = 1;
  if ((2 * SEG) % 97 == 0 && SEG > 1) SEG--;   // keep *97 a bijection
  int nslots = 2 * SEG;
  short* xch = (short*)(ws + OFF_XCH);
  short* xx  = (short*)(ws + OFF_XCH + (size_t)nslots * SLOT_BYTES);

  prep_kernel<<<6144, 256, 0, stream>>>(U, U_in, U_out, W, W_in, W_out, Upk, Wt);
  init0_kernel<<<128, 256, 0, stream>>>(h_f32);

  int s0 = 0;
  while (s0 < NSTEP) {
    int nsteps = NSTEP - s0; if (nsteps > SEG) nsteps = SEG;
    int nt = nsteps + 1;
    int rows = nt * 64;
    int gx = (rows + 127) / 128;
    gemm_xw<<<dim3(gx, 4, 3), 256, 0, stream>>>(X, Wt, b, b_in, b_out, xx,
                                                s0 * 64, rows);
    init_seg_kernel<<<128, 256, 0, stream>>>(h_f32, hinit, flags);
    scan_kernel<<<NGRP * NCOLB, 64, 0, stream>>>(hinit, xch, h_f32, Upk, xx,
                                                 flags, bu_in, bu_out, out,
                                                 s0, nsteps, nt, nslots);
    s0 += nsteps;
  }
}

// Round 14
// 2638.706 us; speedup vs baseline: 1.1464x; 1.1464x over previous
//
#include <hip/hip_runtime.h>
#include <hip/hip_bf16.h>

// ============================================================================
// SimpleGatedUnit. R14 = R12 (best verified: 4 batch domains x 32 col-blocks,
// 1 wave each, data-poll sentinel exchange, frag-major layout, LDS-transpose
// publish) with CRITICAL-PATH COMPUTE TRIMS only:
//  - 4-way split accumulator chains (dep distance 4, not 16): chain latency
//    ~4x24cy + 3 vector adds instead of 16x24cy.
//  - EARLY PUBLISH: stage 1 runs the accin (U_in) chain first, forms g,
//    publishes it, THEN computes accu/z while g is in flight. Stage 2
//    publishes h before the (final-step-only) out store.
//  - All xx loads (both stages) hoisted before the h-poll.
// Exchange protocol, layout, resets, domains: byte-identical to R12.
// ============================================================================

typedef __attribute__((ext_vector_type(4))) float  f32x4;
typedef __attribute__((ext_vector_type(4))) float  floatx4;
typedef __attribute__((ext_vector_type(8))) short  short8;
typedef __attribute__((ext_vector_type(4))) short  short4v;
typedef __attribute__((ext_vector_type(2))) int    int2v;

#define NSTEP  511
#define NGRP   4           // independent batch domains (16 rows each)
#define NCOLB  32          // column blocks per domain (16 cols each)
#define NAN_S  ((short)0x7FFF)

// ws layout (bytes)
#define OFF_HB0  4096                     // h bf16 frag-major, parity 0 (64 KB: 4 grp x 16 KB)
#define OFF_HB1  (OFF_HB0 + 65536)        // h parity 1
#define OFF_GB0  (OFF_HB1 + 65536)        // g parity 0
#define OFF_GB1  (OFF_GB0 + 65536)        // g parity 1
#define OFF_HF32 (OFF_GB1 + 65536)        // h fp32 [64][512] row-major (128 KB)
#define OFF_UPK  (OFF_HF32 + 131072)      // packed U,U_in,U_out bf16  (1.5 MB)
#define OFF_WT   (OFF_UPK + 1572864)      // W^T bf16 [3][512 n][512 k](1.5 MB)
#define OFF_XX   (OFF_WT + 1572864)       // xx,x_in,x_out bf16 segment buffer
#define PER_T_BYTES (3u * 64u * 512u * 2u)  // xx bytes per time row (196608)

__device__ __forceinline__ float b2f(short s) {
  unsigned u = ((unsigned)(unsigned short)s) << 16;
  return __builtin_bit_cast(float, u);
}
__device__ __forceinline__ short f2b(float f) {  // RNE fp32->bf16
  unsigned u = __builtin_bit_cast(unsigned, f);
  u += 0x7fffu + ((u >> 16) & 1u);
  return (short)(u >> 16);
}
__device__ __forceinline__ float hsig(float x) {
  return fminf(fmaxf(0.2f * x + 0.5f, 0.0f), 1.0f);
}
__device__ __forceinline__ float softplus_f(float x) {
  return fmaxf(x, 0.0f) + log1pf(expf(-fabsf(x)));
}

// 8B store to the agent coherence point (IC)
__device__ __forceinline__ void st8_cp(short* p, int2v v) {
  asm volatile("global_store_dwordx2 %0, %1, off sc0 sc1"
               :: "v"(p), "v"(v) : "memory");
}

// 16 x 16B fragment loads from IC in ONE asm block. Frag-major (per group):
// per-kb stride 1024B; 4 bases cover kb {0-3,4-7,8-11,12-15}.
__device__ __forceinline__ void ld_frags16(const short* p0, const short* p1,
                                           const short* p2, const short* p3,
                                           short8 f[16]) {
  short8 f0,f1,f2,f3,f4,f5,f6,f7,f8,f9,f10,f11,f12,f13,f14,f15;
  asm volatile(
    "global_load_dwordx4 %0,  %16, off sc0 sc1\n\t"
    "global_load_dwordx4 %1,  %16, off offset:1024 sc0 sc1\n\t"
    "global_load_dwordx4 %2,  %16, off offset:2048 sc0 sc1\n\t"
    "global_load_dwordx4 %3,  %16, off offset:3072 sc0 sc1\n\t"
    "global_load_dwordx4 %4,  %17, off sc0 sc1\n\t"
    "global_load_dwordx4 %5,  %17, off offset:1024 sc0 sc1\n\t"
    "global_load_dwordx4 %6,  %17, off offset:2048 sc0 sc1\n\t"
    "global_load_dwordx4 %7,  %17, off offset:3072 sc0 sc1\n\t"
    "global_load_dwordx4 %8,  %18, off sc0 sc1\n\t"
    "global_load_dwordx4 %9,  %18, off offset:1024 sc0 sc1\n\t"
    "global_load_dwordx4 %10, %18, off offset:2048 sc0 sc1\n\t"
    "global_load_dwordx4 %11, %18, off offset:3072 sc0 sc1\n\t"
    "global_load_dwordx4 %12, %19, off sc0 sc1\n\t"
    "global_load_dwordx4 %13, %19, off offset:1024 sc0 sc1\n\t"
    "global_load_dwordx4 %14, %19, off offset:2048 sc0 sc1\n\t"
    "global_load_dwordx4 %15, %19, off offset:3072 sc0 sc1\n\t"
    "s_waitcnt vmcnt(0)"
    : "=&v"(f0), "=&v"(f1), "=&v"(f2), "=&v"(f3),
      "=&v"(f4), "=&v"(f5), "=&v"(f6), "=&v"(f7),
      "=&v"(f8), "=&v"(f9), "=&v"(f10), "=&v"(f11),
      "=&v"(f12), "=&v"(f13), "=&v"(f14), "=&v"(f15)
    : "v"(p0), "v"(p1), "v"(p2), "v"(p3)
    : "memory");
  f[0]=f0; f[1]=f1; f[2]=f2; f[3]=f3; f[4]=f4; f[5]=f5; f[6]=f6; f[7]=f7;
  f[8]=f8; f[9]=f9; f[10]=f10; f[11]=f11; f[12]=f12; f[13]=f13; f[14]=f14; f[15]=f15;
}

// poll-load: retry until no lane sees the sentinel in either 8B half
__device__ __forceinline__ void poll_frags16(const short* base, short8 f[16]) {
  const short* q0 = base;
  const short* q1 = base + 2048;
  const short* q2 = base + 4096;
  const short* q3 = base + 6144;
  int guard = 0;
  for (;;) {
    ld_frags16(q0, q1, q2, q3, f);
    int fresh = 1;
    #pragma unroll
    for (int i = 0; i < 16; ++i)
      fresh &= (f[i][0] != NAN_S) & (f[i][4] != NAN_S);
    if (__all(fresh)) break;
    if (++guard > (1 << 13)) break;   // safety valve: degrade, never hang
  }
}

// ---------------------------------------------------------------------------
// prep: pack U mats into B-fragment order bf16; transpose W mats to [n][k]
// Upk[mat][c][kb][lane][j] = U[kb*32 + (lane>>4)*8 + j][c*16 + (lane&15)]
// ---------------------------------------------------------------------------
__global__ __launch_bounds__(256) void prep_kernel(
    const float* __restrict__ U0, const float* __restrict__ U1, const float* __restrict__ U2,
    const float* __restrict__ W0, const float* __restrict__ W1, const float* __restrict__ W2,
    short* __restrict__ Upk, short* __restrict__ Wt)
{
  int e = blockIdx.x * 256 + threadIdx.x;
  if (e < 786432) {
    int mat = e >> 18;
    int rem = e & 262143;
    int c   = rem >> 13;
    int r2  = rem & 8191;
    int kb  = r2 >> 9;
    int r3  = r2 & 511;
    int l = r3 >> 3, j = r3 & 7;
    int k = kb * 32 + ((l >> 4) << 3) + j;
    int d = c * 16 + (l & 15);
    const float* U = (mat == 0) ? U0 : (mat == 1 ? U1 : U2);
    Upk[e] = f2b(U[k * 512 + d]);
  } else if (e < 1572864) {
    int e2 = e - 786432;
    int mat = e2 >> 18;
    int rem = e2 & 262143;
    int n = rem >> 9, k = rem & 511;
    const float* W = (mat == 0) ? W0 : (mat == 1 ? W1 : W2);
    Wt[e2] = f2b(W[k * 512 + n]);
  }
}

// hb1 = h(-1) = zeros (valid); hb0/gb0/gb1 = sentinel; h_f32 = 0
__global__ __launch_bounds__(256) void init_kernel(
    short* hb0, short* hb1, short* gb0, short* gb1, float* h_f32)
{
  int e = blockIdx.x * 256 + threadIdx.x;
  if (e < 32768) {
    hb0[e] = NAN_S; hb1[e] = 0;
    gb0[e] = NAN_S; gb1[e] = NAN_S;
    h_f32[e] = 0.0f;
  }
}

// ---------------------------------------------------------------------------
// GEMM (per segment): out[mat][m][n] = bf16( X-row(base+m) . W[mat][:,n] + b )
// ---------------------------------------------------------------------------
__global__ __launch_bounds__(256) void gemm_xw(
    const float* __restrict__ X, const short* __restrict__ Wt,
    const float* __restrict__ bias0, const float* __restrict__ bias1,
    const float* __restrict__ bias2, short* __restrict__ out,
    int base_row, int cnt_rows)
{
  __shared__ __align__(16) short Al[128][48];
  __shared__ __align__(16) short Bl[128][48];
  const int bm = blockIdx.x, bn = blockIdx.y, mat = blockIdx.z;
  const short* Wm = Wt + (size_t)mat * (512 * 512);
  const float* bias = (mat == 0) ? bias0 : (mat == 1 ? bias1 : bias2);
  short* om = out + (size_t)mat * ((size_t)cnt_rows * 512);
  const int tid = threadIdx.x, lane = tid & 63, wid = tid >> 6;
  const int wm = wid >> 1, wn = wid & 1;
  const int m0 = bm * 128, n0g = bn * 128;
  f32x4 acc[4][4];
  #pragma unroll
  for (int i = 0; i < 4; ++i)
    #pragma unroll
    for (int j = 0; j < 4; ++j) acc[i][j] = (f32x4){0.f, 0.f, 0.f, 0.f};

  for (int k0 = 0; k0 < 512; k0 += 32) {
    #pragma unroll
    for (int i = 0; i < 4; ++i) {
      int q = tid + 256 * i;
      int r = q >> 3, seg = q & 7;
      int ml = m0 + r;
      short4v h4 = {0, 0, 0, 0};
      if (ml < cnt_rows) {
        int gl = base_row + ml;
        int t = gl >> 6, bb = gl & 63;
        floatx4 v = *(const floatx4*)(X + ((size_t)bb * 512 + t) * 512 + k0 + seg * 4);
        h4 = (short4v){ f2b(v[0]), f2b(v[1]), f2b(v[2]), f2b(v[3]) };
      }
      *(short4v*)&Al[r][seg * 4] = h4;
    }
    #pragma unroll
    for (int i = 0; i < 2; ++i) {
      int q = tid + 256 * i;
      int r = q >> 2, seg = q & 3;
      *(short8*)&Bl[r][seg * 8] = *(const short8*)(Wm + (size_t)(n0g + r) * 512 + k0 + seg * 8);
    }
    __syncthreads();
    const int ko = (lane >> 4) * 8;
    short8 af[4], bf4[4];
    #pragma unroll
    for (int mt = 0; mt < 4; ++mt)
      af[mt] = *(const short8*)&Al[wm * 64 + mt * 16 + (lane & 15)][ko];
    #pragma unroll
    for (int nt = 0; nt < 4; ++nt)
      bf4[nt] = *(const short8*)&Bl[wn * 64 + nt * 16 + (lane & 15)][ko];
    #pragma unroll
    for (int mt = 0; mt < 4; ++mt)
      #pragma unroll
      for (int nt = 0; nt < 4; ++nt)
        acc[mt][nt] = __builtin_amdgcn_mfma_f32_16x16x32_bf16(af[mt], bf4[nt], acc[mt][nt], 0, 0, 0);
    __syncthreads();
  }
  const int rq = lane >> 4, cq = lane & 15;
  #pragma unroll
  for (int mt = 0; mt < 4; ++mt) {
    #pragma unroll
    for (int nt = 0; nt < 4; ++nt) {
      int n = n0g + wn * 64 + nt * 16 + cq;
      float bv = bias[n];
      #pragma unroll
      for (int rr = 0; rr < 4; ++rr) {
        int m = m0 + wm * 64 + mt * 16 + rq * 4 + rr;
        if (m < cnt_rows) om[(size_t)m * 512 + n] = f2b(acc[mt][nt][rr] + bv);
      }
    }
  }
}

// ---------------------------------------------------------------------------
// scan segment: 128 blocks x 64 threads (1 wave). Domain g = blk>>5 owns
// batch rows [g*16, g*16+16); block c = blk&31 owns cols [c*16, c*16+16).
// Per-group h/g frag-major (8192 shorts): idx(row,k) = (k>>5)*512
//   + ((k>>3)&3)*128 + (row&15)*8 + (k&7). Group base = g*8192 shorts.
// Publish slice: 256 contiguous shorts at (c>>1)*512 + (c&1)*256.
// ---------------------------------------------------------------------------
__global__ __launch_bounds__(64, 1) void scan_kernel(
    short* hb0, short* hb1, short* gb0, short* gb1, float* h_f32,
    const short* __restrict__ Upk,
    const short* __restrict__ xx,
    const float* __restrict__ bu_in, const float* __restrict__ bu_out,
    float* __restrict__ out,
    int s0, int nsteps, int nt)
{
  __shared__ __align__(16) short Ub[3][16][64][8];   // 48 KB, B-frag-packed
  __shared__ __align__(16) short St[256];            // wave transpose stage
  const int lane = threadIdx.x & 63;
  const int g = blockIdx.x >> 5;          // batch domain
  const int c = blockIdx.x & 31;          // column owner
  {
    const size_t cs = (size_t)c * 8192;
    short8* dst = (short8*)Ub;
    for (int i = lane; i < 3072; i += 64) {
      int mat = i >> 10;
      int rem = i & 1023;
      dst[i] = *(const short8*)(Upk + (size_t)mat * 262144 + cs + (size_t)rem * 8);
    }
  }
  const int colg = c * 16 + (lane & 15);
  const float binr  = bu_in[colg];
  const float boutr = bu_out[colg];
  const size_t XSZ = (size_t)nt * 64 * 512;
  const int gbase = g * 8192;             // group sub-buffer (shorts)
  // consume base: lane's frag position within group buffer
  const int fofs = gbase + ((lane >> 4) << 7) + ((lane & 15) << 3);
  // publish base: block slice + lane*4
  const int pofs = gbase + ((c >> 1) << 9) + ((c & 1) << 8) + (lane << 2);
  // St transpose write index
  const int sw = ((lane & 15) >> 3) * 128 + ((lane >> 4) << 5) + (lane & 7);
  short* hbuf[2] = { hb0, hb1 };
  short* gbuf[2] = { gb0, gb1 };
  const int2v NANPAIR = { 0x7FFF7FFF, 0x7FFF7FFF };

  float hown[4];
  #pragma unroll
  for (int r = 0; r < 4; ++r)
    hown[r] = h_f32[(size_t)(g * 16 + (lane >> 4) * 4 + r) * 512 + colg];
  __syncthreads();

  for (int s = 0; s < nsteps; ++s) {
    const int sg = s0 + s;
    const int p = sg & 1;
    // hoisted xx loads for BOTH stages (cached) — overlap with poll
    float a1[4], a0[4], p1[4], p0[4], q1[4], q0[4];
    #pragma unroll
    for (int r = 0; r < 4; ++r) {
      int gr = g * 16 + (lane >> 4) * 4 + r;
      size_t i1 = ((size_t)(s + 1) * 64 + gr) * 512 + colg;
      size_t i0 = ((size_t)s * 64 + gr) * 512 + colg;
      a1[r] = b2f(xx[i1]);           a0[r] = b2f(xx[i0]);
      p1[r] = b2f(xx[XSZ + i1]);     p0[r] = b2f(xx[XSZ + i0]);
      q1[r] = b2f(xx[2 * XSZ + i1]); q0[r] = b2f(xx[2 * XSZ + i0]);
    }

    // ---- stage 1: poll h(sg-1); accin chain FIRST; publish g; then accu ----
    short8 afr[16];
    poll_frags16(hbuf[p ^ 1] + fofs, afr);
    // poll ok => all col-blocks of this group consumed g(sg-1) => reset slice
    if (sg > 0) st8_cp(gbuf[p ^ 1] + pofs, NANPAIR);

    f32x4 ai[4];
    ai[0] = ai[1] = ai[2] = ai[3] = (f32x4){0.f, 0.f, 0.f, 0.f};
    #pragma unroll
    for (int kb = 0; kb < 16; ++kb) {
      short8 b1 = *((const short8*)Ub + ((1 * 16 + kb) * 64 + lane));
      ai[kb & 3] = __builtin_amdgcn_mfma_f32_16x16x32_bf16(afr[kb], b1, ai[kb & 3], 0, 0, 0);
    }
    f32x4 accin = (ai[0] + ai[1]) + (ai[2] + ai[3]);
    #pragma unroll
    for (int r = 0; r < 4; ++r) {
      float zin = hsig(p1[r] + accin[r] + p0[r] + binr);
      St[sw + r * 8] = f2b(zin * hown[r]);
    }
    // publish g(sg) EARLY: wave-local LDS transpose -> one coalesced 8B store
    st8_cp(gbuf[p] + pofs, *(const int2v*)&St[lane << 2]);

    // accu chain overlaps g's flight
    f32x4 au[4];
    au[0] = au[1] = au[2] = au[3] = (f32x4){0.f, 0.f, 0.f, 0.f};
    #pragma unroll
    for (int kb = 0; kb < 16; ++kb) {
      short8 b0 = *((const short8*)Ub + ((0 * 16 + kb) * 64 + lane));
      au[kb & 3] = __builtin_amdgcn_mfma_f32_16x16x32_bf16(afr[kb], b0, au[kb & 3], 0, 0, 0);
    }
    f32x4 accu = (au[0] + au[1]) + (au[2] + au[3]);
    float zr[4];
    #pragma unroll
    for (int r = 0; r < 4; ++r)
      zr[r] = hsig(a1[r] + accu[r] + a0[r]);

    // ---- stage 2: poll g(sg), acco (4-way chains), publish h ----
    short8 gfr[16];
    poll_frags16(gbuf[p] + fofs, gfr);
    // poll ok => all consumed h(sg-1) => reset own hb[p^1] slice
    st8_cp(hbuf[p ^ 1] + pofs, NANPAIR);
    f32x4 ao[4];
    ao[0] = ao[1] = ao[2] = ao[3] = (f32x4){0.f, 0.f, 0.f, 0.f};
    #pragma unroll
    for (int kb = 0; kb < 16; ++kb) {
      short8 b2 = *((const short8*)Ub + ((2 * 16 + kb) * 64 + lane));
      ao[kb & 3] = __builtin_amdgcn_mfma_f32_16x16x32_bf16(gfr[kb], b2, ao[kb & 3], 0, 0, 0);
    }
    f32x4 acco = (ao[0] + ao[1]) + (ao[2] + ao[3]);
    #pragma unroll
    for (int r = 0; r < 4; ++r) {
      float pre = q1[r] + acco[r] + q0[r] + boutr;
      float zo = softplus_f(pre);
      float hn = (1.0f - zr[r]) * hown[r] + zr[r] * zo;
      hown[r] = hn;
      St[sw + r * 8] = f2b(hn);
    }
    // publish h(sg) EARLY (before the final-step out store)
    st8_cp(hbuf[p] + pofs, *(const int2v*)&St[lane << 2]);
    if (sg == NSTEP - 1) {
      #pragma unroll
      for (int r = 0; r < 4; ++r) {
        int gr = g * 16 + (lane >> 4) * 4 + r;
        out[(size_t)gr * 512 + colg] = hown[r];
      }
    }
  }
  // persist fp32 h for the next segment; drain publishes before exit
  #pragma unroll
  for (int r = 0; r < 4; ++r)
    h_f32[(size_t)(g * 16 + (lane >> 4) * 4 + r) * 512 + colg] = hown[r];
  asm volatile("s_waitcnt vmcnt(0)" ::: "memory");
}

extern "C" void kernel_launch(void* const* d_in, const int* in_sizes, int n_in,
                              void* d_out, int out_size, void* d_ws, size_t ws_size,
                              hipStream_t stream)
{
  const float* X      = (const float*)d_in[0];
  const float* W      = (const float*)d_in[1];
  const float* b      = (const float*)d_in[2];
  const float* W_in   = (const float*)d_in[3];
  const float* b_in   = (const float*)d_in[4];
  const float* W_out  = (const float*)d_in[5];
  const float* b_out  = (const float*)d_in[6];
  const float* U      = (const float*)d_in[7];
  const float* U_in   = (const float*)d_in[8];
  const float* U_out  = (const float*)d_in[9];
  const float* bu_in  = (const float*)d_in[10];
  const float* bu_out = (const float*)d_in[11];
  float* out = (float*)d_out;
  char* ws = (char*)d_ws;
  short* hb0  = (short*)(ws + OFF_HB0);
  short* hb1  = (short*)(ws + OFF_HB1);
  short* gb0  = (short*)(ws + OFF_GB0);
  short* gb1  = (short*)(ws + OFF_GB1);
  float* h_f32= (float*)(ws + OFF_HF32);
  short* Upk  = (short*)(ws + OFF_UPK);
  short* Wt   = (short*)(ws + OFF_WT);
  short* xx   = (short*)(ws + OFF_XX);

  size_t avail = (ws_size > (size_t)OFF_XX) ? ws_size - (size_t)OFF_XX : 0;
  int max_t = (int)(avail / PER_T_BYTES);
  if (max_t > 512) max_t = 512;
  int SEG = max_t - 1;
  if (SEG < 1) SEG = 1;

  prep_kernel<<<6144, 256, 0, stream>>>(U, U_in, U_out, W, W_in, W_out, Upk, Wt);
  init_kernel<<<128, 256, 0, stream>>>(hb0, hb1, gb0, gb1, h_f32);

  int s0 = 0;
  while (s0 < NSTEP) {
    int nsteps = NSTEP - s0; if (nsteps > SEG) nsteps = SEG;
    int nt = nsteps + 1;
    int rows = nt * 64;
    int gx = (rows + 127) / 128;
    gemm_xw<<<dim3(gx, 4, 3), 256, 0, stream>>>(X, Wt, b, b_in, b_out, xx,
                                                s0 * 64, rows);
    scan_kernel<<<NGRP * NCOLB, 64, 0, stream>>>(hb0, hb1, gb0, gb1, h_f32,
                                                 Upk, xx, bu_in, bu_out, out,
                                                 s0, nsteps, nt);
    s0 += nsteps;
  }
}